// Round 2
// baseline (233.149 us; speedup 1.0000x reference)
//
#include <hip/hip_runtime.h>

#define NB 32          // batch
#define NT 1024        // input time steps
#define ND 384         // feature dim
#define ND4 (ND / 4)   // 96 float4 per frame

// One block per batch: inclusive scan of durations[b,:] in LDS, then each
// thread t scatters its index into idx[b][p] for p in [csum-dur, csum).
// Also records totals[b] = csum[NT-1].
__global__ void __launch_bounds__(NT)
scan_scatter_kernel(const int* __restrict__ dur,
                    int* __restrict__ idx,
                    int* __restrict__ totals,
                    int max_len) {
    __shared__ int s[NT];
    const int b = blockIdx.x;
    const int t = threadIdx.x;
    const int d = dur[b * NT + t];
    s[t] = d;
    __syncthreads();
    #pragma unroll
    for (int off = 1; off < NT; off <<= 1) {
        int add = (t >= off) ? s[t - off] : 0;
        __syncthreads();
        s[t] += add;
        __syncthreads();
    }
    const int csum_t = s[t];           // inclusive
    int* idx_b = idx + (size_t)b * max_len;
    for (int p = csum_t - d; p < csum_t; ++p)
        idx_b[p] = t;                  // scatter: avg 3.5 writes, ranges adjacent across threads
    if (t == NT - 1)
        totals[b] = csum_t;
}

// grid = (blocks_x, NB). Pure streaming gather: per float4 element, read the
// precomputed frame index (broadcast within wave), copy 16B, or write zeros
// in the padding region.
__global__ void __launch_bounds__(256)
gather_kernel(const float4* __restrict__ enc,
              const int* __restrict__ idx,
              const int* __restrict__ totals,
              float4* __restrict__ out,
              int max_len, int f4_per_batch) {
    const int b = blockIdx.y;
    const int total_f4 = totals[b] * ND4;   // uniform -> scalar load
    const int* idx_b = idx + (size_t)b * max_len;
    const size_t enc_base = (size_t)b * NT * ND4;
    const size_t out_base = (size_t)b * (size_t)max_len * ND4;
    const int stride = gridDim.x * blockDim.x;

    for (int j = blockIdx.x * blockDim.x + threadIdx.x; j < f4_per_batch; j += stride) {
        float4 val = make_float4(0.f, 0.f, 0.f, 0.f);
        if (j < total_f4) {
            const int p  = j / ND4;          // const divisor -> magic mul
            const int d4 = j - p * ND4;
            const int t  = idx_b[p];         // ~same p across a wave -> L1 broadcast
            val = enc[enc_base + (size_t)t * ND4 + d4];
        }
        out[out_base + j] = val;
    }
}

extern "C" void kernel_launch(void* const* d_in, const int* in_sizes, int n_in,
                              void* d_out, int out_size, void* d_ws, size_t ws_size,
                              hipStream_t stream) {
    const float* enc = (const float*)d_in[0];
    const int*   dur = (const int*)d_in[1];
    float* out = (float*)d_out;

    const int max_len = out_size / (NB * ND);   // out_size = NB*max_len*ND

    // ws layout: [totals: NB ints][idx: NB*max_len ints] (~475 KB total)
    int* totals = (int*)d_ws;
    int* idx    = totals + NB;

    scan_scatter_kernel<<<NB, NT, 0, stream>>>(dur, idx, totals, max_len);

    const int f4pb = max_len * ND4;
    const int blocks_x = (f4pb + 1023) / 1024;  // ~4 float4 per thread
    dim3 grid(blocks_x, NB);
    gather_kernel<<<grid, 256, 0, stream>>>(
        (const float4*)enc, idx, totals, (float4*)out, max_len, f4pb);
}

// Round 4
// 222.021 us; speedup vs baseline: 1.0501x; 1.0501x over previous
//
#include <hip/hip_runtime.h>

#define NB 32          // batch
#define NT 1024        // input time steps
#define ND 384         // feature dim
#define ND4 (ND / 4)   // 96 float4 per frame
#define CHUNK 1024     // float4s per gather block (256 thr x 4 unroll)

typedef float vfloat4 __attribute__((ext_vector_type(4)));  // native vec: OK for nontemporal builtins

// One block per batch: inclusive scan of durations[b,:] in LDS, then each
// thread t scatters its index into idx[b][p] for p in [csum-dur, csum).
// Pad region idx[total..max_len) is zero-filled so the gather can load it
// unconditionally (d_ws is poisoned 0xAA by the harness).
__global__ void __launch_bounds__(NT)
scan_scatter_kernel(const int* __restrict__ dur,
                    int* __restrict__ idx,
                    int* __restrict__ totals,
                    int max_len) {
    __shared__ int s[NT];
    const int b = blockIdx.x;
    const int t = threadIdx.x;
    const int d = dur[b * NT + t];
    s[t] = d;
    __syncthreads();
    #pragma unroll
    for (int off = 1; off < NT; off <<= 1) {
        int add = (t >= off) ? s[t - off] : 0;
        __syncthreads();
        s[t] += add;
        __syncthreads();
    }
    const int csum_t = s[t];           // inclusive
    const int total  = s[NT - 1];      // safe: loop ends with a barrier
    int* idx_b = idx + (size_t)b * max_len;
    for (int p = csum_t - d; p < csum_t; ++p)
        idx_b[p] = t;
    for (int p = total + t; p < max_len; p += NT)
        idx_b[p] = 0;                  // pad -> frame 0 (masked to zero in gather)
    if (t == NT - 1)
        totals[b] = total;
}

// grid = (ceil(f4pb/CHUNK), NB). Each block owns a contiguous CHUNK of
// float4s of one batch's output. 4-wide static unroll: 4 independent idx
// loads, then 4 enc loads, then 4 nontemporal stores — two dependence
// levels per thread instead of four serialized load round-trips.
__global__ void __launch_bounds__(256)
gather_kernel(const vfloat4* __restrict__ enc,
              const int* __restrict__ idx,
              const int* __restrict__ totals,
              vfloat4* __restrict__ out,
              int max_len, int f4_per_batch) {
    const int b = blockIdx.y;
    const int total_f4 = totals[b] * ND4;            // wave-uniform
    const int* idx_b = idx + (size_t)b * max_len;
    const vfloat4* enc_b = enc + (size_t)b * NT * ND4;
    vfloat4* out_b = out + (size_t)b * (size_t)max_len * ND4;

    const int base = blockIdx.x * CHUNK + threadIdx.x;

    int j[4], t[4], d4[4];
    #pragma unroll
    for (int k = 0; k < 4; ++k) {
        j[k] = base + k * 256;
        const int jc = j[k] < f4_per_batch ? j[k] : f4_per_batch - 1;
        const int p  = jc / ND4;                     // const-divisor magic mul
        d4[k] = jc - p * ND4;
        t[k]  = idx_b[p];                            // 4 independent loads
    }
    vfloat4 v[4];
    #pragma unroll
    for (int k = 0; k < 4; ++k)
        v[k] = enc_b[(size_t)t[k] * ND4 + d4[k]];    // 4 independent loads
    #pragma unroll
    for (int k = 0; k < 4; ++k) {
        if (j[k] >= total_f4)
            v[k] = (vfloat4){0.f, 0.f, 0.f, 0.f};    // zero-pad region
        if (j[k] < f4_per_batch)
            __builtin_nontemporal_store(v[k], &out_b[j[k]]);
    }
}

extern "C" void kernel_launch(void* const* d_in, const int* in_sizes, int n_in,
                              void* d_out, int out_size, void* d_ws, size_t ws_size,
                              hipStream_t stream) {
    const float* enc = (const float*)d_in[0];
    const int*   dur = (const int*)d_in[1];
    float* out = (float*)d_out;

    const int max_len = out_size / (NB * ND);   // out_size = NB*max_len*ND

    // ws layout: [totals: NB ints][idx: NB*max_len ints] (~475 KB)
    int* totals = (int*)d_ws;
    int* idx    = totals + NB;

    scan_scatter_kernel<<<NB, NT, 0, stream>>>(dur, idx, totals, max_len);

    const int f4pb = max_len * ND4;
    const int blocks_x = (f4pb + CHUNK - 1) / CHUNK;
    dim3 grid(blocks_x, NB);
    gather_kernel<<<grid, 256, 0, stream>>>(
        (const vfloat4*)enc, idx, totals, (vfloat4*)out, max_len, f4pb);
}

// Round 5
// 221.379 us; speedup vs baseline: 1.0532x; 1.0029x over previous
//
#include <hip/hip_runtime.h>

#define NB 32            // batch
#define NT 1024          // input time steps
#define ND 384           // feature dim
#define ND4 (ND / 4)     // 96 float4 per frame
#define FPB 16           // output frames per gather block
#define CHUNK_F4 (FPB * ND4)   // 1536 float4 per block
#define THREADS 256
#define PASSES (CHUNK_F4 / THREADS)  // 6

typedef float vfloat4 __attribute__((ext_vector_type(4)));

// One block per batch: inclusive scan of durations[b,:] in LDS, then each
// thread t scatters its index into idx[b][p] for p in [csum-dur, csum).
// Pad region idx[total..max_len) -> 0 so gather loads are always in-bounds.
__global__ void __launch_bounds__(NT)
scan_scatter_kernel(const int* __restrict__ dur,
                    int* __restrict__ idx,
                    int* __restrict__ totals,
                    int max_len) {
    __shared__ int s[NT];
    const int b = blockIdx.x;
    const int t = threadIdx.x;
    const int d = dur[b * NT + t];
    s[t] = d;
    __syncthreads();
    #pragma unroll
    for (int off = 1; off < NT; off <<= 1) {
        int add = (t >= off) ? s[t - off] : 0;
        __syncthreads();
        s[t] += add;
        __syncthreads();
    }
    const int csum_t = s[t];           // inclusive
    const int total  = s[NT - 1];      // loop ends with a barrier -> safe
    int* idx_b = idx + (size_t)b * max_len;
    for (int p = csum_t - d; p < csum_t; ++p)
        idx_b[p] = t;
    for (int p = total + t; p < max_len; p += NT)
        idx_b[p] = 0;                  // pad -> frame 0 (masked to zero in gather)
    if (t == NT - 1)
        totals[b] = total;
}

// grid = (ceil(max_len/FPB), NB). Frame-aligned chunks: block loads its <=16
// source frames into LDS ONCE (unique bytes from HBM; intra-block reuse is
// free), then streams LDS -> out with coalesced nontemporal stores.
__global__ void __launch_bounds__(THREADS)
gather_kernel(const vfloat4* __restrict__ enc,
              const int* __restrict__ idx,
              const int* __restrict__ totals,
              vfloat4* __restrict__ out,
              int max_len, int f4_per_batch) {
    __shared__ int s_t[FPB];
    __shared__ vfloat4 s_frames[CHUNK_F4];   // 24 KB

    const int b  = blockIdx.y;
    const int p0 = blockIdx.x * FPB;
    const int* idx_b = idx + (size_t)b * max_len;

    if (threadIdx.x < FPB) {
        int p = p0 + threadIdx.x;
        if (p > max_len - 1) p = max_len - 1;   // clamp tail (idx in-bounds)
        s_t[threadIdx.x] = idx_b[p];
    }
    __syncthreads();

    const vfloat4* enc_b = enc + (size_t)b * NT * ND4;
    #pragma unroll
    for (int k = 0; k < PASSES; ++k) {
        const int i    = k * THREADS + threadIdx.x;
        const int slot = i / ND4;               // const-divisor magic mul
        const int d4   = i - slot * ND4;
        s_frames[i] = enc_b[(size_t)s_t[slot] * ND4 + d4];  // coalesced per frame
    }
    __syncthreads();

    const int total_f4 = totals[b] * ND4;       // wave-uniform
    vfloat4* out_b = out + (size_t)b * (size_t)max_len * ND4;
    const int jbase = p0 * ND4;
    #pragma unroll
    for (int k = 0; k < PASSES; ++k) {
        const int i = k * THREADS + threadIdx.x;
        const int j = jbase + i;
        if (j < f4_per_batch) {
            vfloat4 v = s_frames[i];
            if (j >= total_f4) v = (vfloat4){0.f, 0.f, 0.f, 0.f};
            __builtin_nontemporal_store(v, &out_b[j]);
        }
    }
}

extern "C" void kernel_launch(void* const* d_in, const int* in_sizes, int n_in,
                              void* d_out, int out_size, void* d_ws, size_t ws_size,
                              hipStream_t stream) {
    const float* enc = (const float*)d_in[0];
    const int*   dur = (const int*)d_in[1];
    float* out = (float*)d_out;

    const int max_len = out_size / (NB * ND);   // out_size = NB*max_len*ND

    // ws layout: [totals: NB ints][idx: NB*max_len ints] (~475 KB)
    int* totals = (int*)d_ws;
    int* idx    = totals + NB;

    scan_scatter_kernel<<<NB, NT, 0, stream>>>(dur, idx, totals, max_len);

    const int f4pb = max_len * ND4;
    const int blocks_x = (max_len + FPB - 1) / FPB;
    dim3 grid(blocks_x, NB);
    gather_kernel<<<grid, THREADS, 0, stream>>>(
        (const vfloat4*)enc, idx, totals, (vfloat4*)out, max_len, f4pb);
}

// Round 6
// 220.917 us; speedup vs baseline: 1.0554x; 1.0021x over previous
//
#include <hip/hip_runtime.h>

#define NB 32            // batch
#define NT 1024          // input time steps
#define ND 384           // feature dim
#define ND4 (ND / 4)     // 96 float4 per frame
#define THREADS 256
#define ILP 8
#define CHUNK (THREADS * ILP)   // 2048 float4 per gather block

typedef float vfloat4 __attribute__((ext_vector_type(4)));

// One block per batch. Wave-shuffle inclusive scan (2 barriers, not 20),
// then scatter t into idx[b][p] for p in [csum-d, csum); zero-fill pad.
__global__ void __launch_bounds__(NT)
scan_scatter_kernel(const int* __restrict__ dur,
                    int* __restrict__ idx,
                    int* __restrict__ totals,
                    int max_len) {
    __shared__ int wsum[16];
    const int b = blockIdx.x;
    const int t = threadIdx.x;
    const int lane = t & 63;
    const int w = t >> 6;                 // wave id, 16 waves
    const int d = dur[b * NT + t];

    // intra-wave inclusive scan (64 lanes, 6 shuffle steps, no barriers)
    int x = d;
    #pragma unroll
    for (int off = 1; off < 64; off <<= 1) {
        int y = __shfl_up(x, off, 64);
        if (lane >= off) x += y;
    }
    if (lane == 63) wsum[w] = x;
    __syncthreads();
    if (w == 0) {
        int v = (lane < 16) ? wsum[lane] : 0;
        #pragma unroll
        for (int off = 1; off < 16; off <<= 1) {
            int y = __shfl_up(v, off, 64);
            if (lane >= off) v += y;
        }
        if (lane < 16) wsum[lane] = v;    // inclusive per-wave totals
    }
    __syncthreads();
    const int csum_t = x + (w ? wsum[w - 1] : 0);
    const int total  = wsum[15];

    int* idx_b = idx + (size_t)b * max_len;
    for (int p = csum_t - d; p < csum_t; ++p)
        idx_b[p] = t;                     // scatter source index
    for (int p = total + t; p < max_len; p += NT)
        idx_b[p] = 0;                     // pad -> frame 0 (masked to zero later)
    if (t == NT - 1)
        totals[b] = total;
}

// grid = (ceil(f4pb/CHUNK), NB). Direct streaming gather, 8-deep ILP:
// 8 independent idx loads -> 8 independent enc loads -> 8 NT stores.
__global__ void __launch_bounds__(THREADS)
gather_kernel(const vfloat4* __restrict__ enc,
              const int* __restrict__ idx,
              const int* __restrict__ totals,
              vfloat4* __restrict__ out,
              int max_len, int f4_per_batch) {
    const int b = blockIdx.y;
    const int total_f4 = totals[b] * ND4;            // wave-uniform
    const int* idx_b = idx + (size_t)b * max_len;
    const vfloat4* enc_b = enc + (size_t)b * NT * ND4;
    vfloat4* out_b = out + (size_t)b * (size_t)max_len * ND4;

    const int base = blockIdx.x * CHUNK + threadIdx.x;

    int j[ILP], t[ILP], d4[ILP];
    #pragma unroll
    for (int k = 0; k < ILP; ++k) {
        j[k] = base + k * THREADS;
        const int jc = j[k] < f4_per_batch ? j[k] : f4_per_batch - 1;
        const int p  = jc / ND4;                     // const-divisor magic mul
        d4[k] = jc - p * ND4;
        t[k]  = idx_b[p];                            // independent loads
    }
    vfloat4 v[ILP];
    #pragma unroll
    for (int k = 0; k < ILP; ++k)
        v[k] = enc_b[(size_t)t[k] * ND4 + d4[k]];    // independent loads
    #pragma unroll
    for (int k = 0; k < ILP; ++k) {
        if (j[k] >= total_f4)
            v[k] = (vfloat4){0.f, 0.f, 0.f, 0.f};    // zero-pad region
        if (j[k] < f4_per_batch)
            __builtin_nontemporal_store(v[k], &out_b[j[k]]);
    }
}

extern "C" void kernel_launch(void* const* d_in, const int* in_sizes, int n_in,
                              void* d_out, int out_size, void* d_ws, size_t ws_size,
                              hipStream_t stream) {
    const float* enc = (const float*)d_in[0];
    const int*   dur = (const int*)d_in[1];
    float* out = (float*)d_out;

    const int max_len = out_size / (NB * ND);   // out_size = NB*max_len*ND

    // ws layout: [totals: NB ints][idx: NB*max_len ints] (~475 KB)
    int* totals = (int*)d_ws;
    int* idx    = totals + NB;

    scan_scatter_kernel<<<NB, NT, 0, stream>>>(dur, idx, totals, max_len);

    const int f4pb = max_len * ND4;
    const int blocks_x = (f4pb + CHUNK - 1) / CHUNK;
    dim3 grid(blocks_x, NB);
    gather_kernel<<<grid, THREADS, 0, stream>>>(
        (const vfloat4*)enc, idx, totals, (vfloat4*)out, max_len, f4pb);
}